// Round 13
// baseline (49.414 us; speedup 1.0000x reference)
//
#include <hip/hip_runtime.h>
#include <hip/hip_bf16.h>

#define IN_F 8192
#define OUT_F 8192
#define BATCH 64
#define KSPLIT 8

typedef __attribute__((ext_vector_type(8))) short  bf16x8_t;  // 8 bf16 (4 VGPRs)
typedef __attribute__((ext_vector_type(8))) ushort u16x8_t;   // 16B store unit
typedef __attribute__((ext_vector_type(4))) float  f32x4_t;   // MFMA accumulator

// ---------------------------------------------------------------------------
// x fp32 [64][8192] -> xb bf16, fragment-major: xb[(k8*64 + row)*8 + j]
// ---------------------------------------------------------------------------
__global__ void wol_xconv(const float* __restrict__ x,
                          ushort* __restrict__ xb) {
    int g = blockIdx.x * 256 + threadIdx.x;   // 65536 threads
    int k8  = g & 1023;
    int row = g >> 10;
    const float4* src = (const float4*)&x[row * IN_F + k8 * 8];
    float4 a = src[0], b = src[1];
    float f[8] = {a.x, a.y, a.z, a.w, b.x, b.y, b.z, b.w};
    union { ushort u[8]; bf16x8_t v; } o;
#pragma unroll
    for (int j = 0; j < 8; ++j) {
        __hip_bfloat16 hb = __float2bfloat16(f[j]);
        o.u[j] = *reinterpret_cast<ushort*>(&hb);
    }
    *(bf16x8_t*)&xb[((size_t)k8 * 64 + row) * 8] = o.v;
}

// ---------------------------------------------------------------------------
// Stage A: MFMA GEMM, in-register dequant, A staged in LDS, no atomics.
// KSPLIT=8: grid 32 N-tiles x 8 K-splits = 256 blocks x 512 thr
//           = 1 block/CU, 128 KB LDS holds the block's FULL 1024-K A-slice.
// *** ROUND 13: launched TWICE (identical output) as an instrument to
// *** measure this dispatch's true graph-replay duration:
// ***   total_R13 - total_R12 = one wol_mfma duration.
// ---------------------------------------------------------------------------
__global__ void __launch_bounds__(512, 4)
wol_mfma(const int*    __restrict__ qw,
         const int*    __restrict__ qz,
         const float*  __restrict__ sc,
         const ushort* __restrict__ xb,
         ushort*       __restrict__ part) {
    const int nt   = blockIdx.x & 31;
    const int ks   = blockIdx.x >> 5;           // 0..7
    const int wid  = threadIdx.x >> 6;
    const int lane = threadIdx.x & 63;
    const int ln   = lane & 15;
    const int kb   = lane >> 4;                 // k-subblock 0..3
    const int colbase = nt * 256 + wid * 32;    // wave's 32 columns
    const int k0      = ks * 1024;              // block K range (8 groups)
    const int gbase   = k0 >> 7;
    const int qrowb   = k0 >> 3;                // 128 qrows per block

    // ---- group-0 prefetch (in flight across LDS staging + barrier) ----
    unsigned qc[4][2]; float svc[2]; unsigned zwc[2];
#pragma unroll
    for (int kt = 0; kt < 4; ++kt)
#pragma unroll
        for (int nj = 0; nj < 2; ++nj)
            qc[kt][nj] = (unsigned)qw[(size_t)(qrowb + kt * 4 + kb) * OUT_F +
                                      colbase + nj * 16 + ln];
#pragma unroll
    for (int nj = 0; nj < 2; ++nj) {
        const int c = colbase + nj * 16 + ln;
        svc[nj] = sc[gbase * OUT_F + c];
        zwc[nj] = (unsigned)qz[gbase * (OUT_F / 8) + (c >> 3)];
    }
    __builtin_amdgcn_sched_barrier(0);          // pin group-0 loads here

    // ---- stage block's A slice: 128 qrows x 64 rows x 8 bf16 = 128 KB ----
    __shared__ ushort lds_x[128 * 64 * 8];
    {
        const bf16x8_t* src = (const bf16x8_t*)xb + (size_t)ks * 8192;
        bf16x8_t*       dst = (bf16x8_t*)lds_x;
#pragma unroll
        for (int i = 0; i < 16; ++i)
            dst[i * 512 + threadIdx.x] = src[i * 512 + threadIdx.x];
    }
    __syncthreads();

    f32x4_t acc[4][2];
#pragma unroll
    for (int mi = 0; mi < 4; ++mi)
#pragma unroll
        for (int nj = 0; nj < 2; ++nj) acc[mi][nj] = (f32x4_t)0.0f;

#pragma unroll 1
    for (int g = 0; g < 8; ++g) {               // 8 quant groups of 128 K
        // ---- prefetch group g+1 BEFORE computing group g, pinned ----
        unsigned qn[4][2]; float svn[2]; unsigned zwn[2];
        if (g < 7) {
            const int qrow1 = qrowb + (g + 1) * 16;
#pragma unroll
            for (int kt = 0; kt < 4; ++kt)
#pragma unroll
                for (int nj = 0; nj < 2; ++nj)
                    qn[kt][nj] = (unsigned)qw[(size_t)(qrow1 + kt * 4 + kb) * OUT_F +
                                              colbase + nj * 16 + ln];
#pragma unroll
            for (int nj = 0; nj < 2; ++nj) {
                const int c = colbase + nj * 16 + ln;
                svn[nj] = sc[(gbase + g + 1) * OUT_F + c];
                zwn[nj] = (unsigned)qz[(gbase + g + 1) * (OUT_F / 8) + (c >> 3)];
            }
            __builtin_amdgcn_sched_barrier(0);  // loads stay ABOVE the compute
        }

        float s[2], dz[2];
#pragma unroll
        for (int nj = 0; nj < 2; ++nj) {
            const unsigned zp = ((zwc[nj] >> ((ln & 7) * 4)) + 1u) & 15u;  // zp-1 stored
            s[nj]  = svc[nj];
            dz[nj] = -(float)zp * svc[nj];      // w = nib*s + dz
        }

#pragma unroll
        for (int kt = 0; kt < 4; ++kt) {        // 4 K-steps of 32
            const int lrow = g * 16 + kt * 4 + kb;   // local qrow 0..127
            bf16x8_t af[4];
#pragma unroll
            for (int mi = 0; mi < 4; ++mi)
                af[mi] = *(const bf16x8_t*)&lds_x[(lrow * 64 + mi * 16 + ln) * 8];
#pragma unroll
            for (int nj = 0; nj < 2; ++nj) {
                const unsigned qv  = qc[kt][nj];
                const unsigned qlo = qv & 0x0F0F0F0Fu;         // nibbles 0,2,4,6
                const unsigned qhi = (qv >> 4) & 0x0F0F0F0Fu;  // nibbles 1,3,5,7
                union { ushort u[8]; bf16x8_t v; } bu;
#pragma unroll
                for (int b = 0; b < 4; ++b) {
                    const float fe = (float)((qlo >> (8 * b)) & 0xFFu);  // v_cvt_f32_ubyteN
                    const float fo = (float)((qhi >> (8 * b)) & 0xFFu);
                    const float we = fe * s[nj] + dz[nj];
                    const float wo = fo * s[nj] + dz[nj];
                    __hip_bfloat16 he = __float2bfloat16(we);
                    __hip_bfloat16 ho = __float2bfloat16(wo);
                    bu.u[2 * b]     = *reinterpret_cast<ushort*>(&he);
                    bu.u[2 * b + 1] = *reinterpret_cast<ushort*>(&ho);
                }
#pragma unroll
                for (int mi = 0; mi < 4; ++mi)
                    acc[mi][nj] = __builtin_amdgcn_mfma_f32_16x16x32_bf16(
                        af[mi], bu.v, acc[mi][nj], 0, 0, 0);
            }
        }

        if (g < 7) {                            // rotate prefetch buffers
#pragma unroll
            for (int kt = 0; kt < 4; ++kt)
#pragma unroll
                for (int nj = 0; nj < 2; ++nj) qc[kt][nj] = qn[kt][nj];
#pragma unroll
            for (int nj = 0; nj < 2; ++nj) { svc[nj] = svn[nj]; zwc[nj] = zwn[nj]; }
        }
    }

    // ---- epilogue: bf16 fragment-major partials, one 64B store/thread ----
    union { ushort u[32]; u16x8_t v8[4]; } ob;
#pragma unroll
    for (int mi = 0; mi < 4; ++mi)
#pragma unroll
        for (int nj = 0; nj < 2; ++nj)
#pragma unroll
            for (int j = 0; j < 4; ++j) {
                __hip_bfloat16 h = __float2bfloat16(acc[mi][nj][j]);
                ob.u[(mi * 2 + nj) * 4 + j] = *reinterpret_cast<ushort*>(&h);
            }
    u16x8_t* pb = (u16x8_t*)part + ((size_t)(ks * 32 + nt) * 512 + threadIdx.x) * 4;
#pragma unroll
    for (int i = 0; i < 4; ++i) pb[i] = ob.v8[i];
}

// ---------------------------------------------------------------------------
// Stage B: sum 8 bf16 K-split partials (fragment layout) + bias -> out.
// ---------------------------------------------------------------------------
__global__ void __launch_bounds__(256)
wol_reduce(const ushort* __restrict__ part,
           const float*  __restrict__ bias,
           float* __restrict__ out) {
    const int u   = blockIdx.x * 256 + threadIdx.x;
    const int v8  = u & 3;               // which ushort8 of the thread's 32
    const int tid = (u >> 2) & 511;      // stage-A thread id
    const int nt  = u >> 11;             // stage-A N-tile

    float s[8];
#pragma unroll
    for (int e = 0; e < 8; ++e) s[e] = 0.0f;
#pragma unroll
    for (int ks = 0; ks < KSPLIT; ++ks) {
        const u16x8_t p = *((const u16x8_t*)part +
                            (((size_t)(ks * 32 + nt) * 512 + tid) * 4 + v8));
#pragma unroll
        for (int e = 0; e < 8; ++e) {
            union { unsigned b; float f; } cv;
            cv.b = ((unsigned)(ushort)p[e]) << 16;   // bf16 -> f32 exact
            s[e] += cv.f;
        }
    }

    const int wid = tid >> 6, lane = tid & 63;
    const int ln = lane & 15, kb = lane >> 4;
#pragma unroll
    for (int e = 0; e < 8; ++e) {
        const int idx = v8 * 8 + e;                  // (mi*2+nj)*4 + j
        const int mi = idx >> 3, nj = (idx >> 2) & 1, j = idx & 3;
        const int row = mi * 16 + kb * 4 + j;
        const int col = nt * 256 + wid * 32 + nj * 16 + ln;
        out[(size_t)row * OUT_F + col] = s[e] + bias[col];
    }
}

extern "C" void kernel_launch(void* const* d_in, const int* in_sizes, int n_in,
                              void* d_out, int out_size, void* d_ws, size_t ws_size,
                              hipStream_t stream) {
    const float* x    = (const float*)d_in[0];
    const int*   qw   = (const int*)d_in[1];
    const int*   qz   = (const int*)d_in[2];
    const float* sc   = (const float*)d_in[3];
    const float* bias = (const float*)d_in[4];
    float* out = (float*)d_out;

    ushort* xb  = (ushort*)d_ws;                         // 1 MiB bf16 activations
    ushort* prt = (ushort*)((char*)d_ws + (2u << 20));   // 8 MiB bf16 partials

    (void)in_sizes; (void)n_in; (void)ws_size; (void)out_size;

    wol_xconv<<<256, 256, 0, stream>>>(x, xb);
    // INSTRUMENT: launched twice, writes bit-identical partials both times.
    // total_R13 - total_R12 = one wol_mfma dispatch duration under graph replay.
    wol_mfma<<<256, 512, 0, stream>>>(qw, qz, sc, xb, prt);
    wol_mfma<<<256, 512, 0, stream>>>(qw, qz, sc, xb, prt);
    wol_reduce<<<256, 256, 0, stream>>>(prt, bias, out);
}

// Round 14
// 26.819 us; speedup vs baseline: 1.8425x; 1.8425x over previous
//
#include <hip/hip_runtime.h>
#include <hip/hip_bf16.h>

#define IN_F 8192
#define OUT_F 8192
#define BATCH 64
#define KSPLIT 8

typedef __attribute__((ext_vector_type(8))) short  bf16x8_t;  // 8 bf16 (4 VGPRs)
typedef __attribute__((ext_vector_type(8))) ushort u16x8_t;   // 16B store unit
typedef __attribute__((ext_vector_type(4))) float  f32x4_t;   // MFMA accumulator

// ---------------------------------------------------------------------------
// Fused stage-A: x fp32 -> bf16 LDS conversion + MFMA GEMM + bf16 partials.
// Grid: 32 N-tiles x 8 K-splits = 256 blocks x 512 thr (1 block/CU).
// LDS: XOR-swizzled row-major x-slice [64 rows][1024 k] bf16 = 128 KB:
//   byte = row*2048 + k8l*16,  byte ^= (row&7)<<4
// - staging: wave reads one row's k-chunk coalesced (2KB/instr, L2-hot),
//   converts fp32->bf16 (RNE, same as old xconv), writes conflict-free.
// - af reads: (mi*16+ln)*2048 + (kbyte ^ ((ln&7)<<4)) -> 8 lanes/bank-quad
//   (optimal b128 distribution, same as the old fragment-major layout).
// K-loop, q prefetch pipeline, dequant, epilogue: identical to R12.
// ---------------------------------------------------------------------------
__global__ void __launch_bounds__(512, 4)
wol_mfma(const float*  __restrict__ x,
         const int*    __restrict__ qw,
         const int*    __restrict__ qz,
         const float*  __restrict__ sc,
         ushort*       __restrict__ part) {
    const int nt   = blockIdx.x & 31;
    const int ks   = blockIdx.x >> 5;           // 0..7
    const int wid  = threadIdx.x >> 6;
    const int lane = threadIdx.x & 63;
    const int ln   = lane & 15;
    const int kb   = lane >> 4;                 // k-subblock 0..3
    const int colbase = nt * 256 + wid * 32;    // wave's 32 columns
    const int k0      = ks * 1024;              // block K range (8 groups)
    const int gbase   = k0 >> 7;
    const int qrowb   = k0 >> 3;                // 128 qrows per block

    // ---- group-0 prefetch (in flight across LDS staging + barrier) ----
    unsigned qc[4][2]; float svc[2]; unsigned zwc[2];
#pragma unroll
    for (int kt = 0; kt < 4; ++kt)
#pragma unroll
        for (int nj = 0; nj < 2; ++nj)
            qc[kt][nj] = (unsigned)qw[(size_t)(qrowb + kt * 4 + kb) * OUT_F +
                                      colbase + nj * 16 + ln];
#pragma unroll
    for (int nj = 0; nj < 2; ++nj) {
        const int c = colbase + nj * 16 + ln;
        svc[nj] = sc[gbase * OUT_F + c];
        zwc[nj] = (unsigned)qz[gbase * (OUT_F / 8) + (c >> 3)];
    }
    __builtin_amdgcn_sched_barrier(0);          // pin group-0 loads here

    // ---- fused staging: x fp32 -> bf16 swizzled row-major LDS (128 KB) ----
    __shared__ ushort lds_x[128 * 64 * 8];
    {
#pragma unroll
        for (int i = 0; i < 16; ++i) {
            const int idx = i * 512 + (int)threadIdx.x;  // 8192 frags
            const int row = idx >> 7;                    // 0..63 (1 row/wave)
            const int k8l = idx & 127;                   // 0..127
            const float4* sp = (const float4*)&x[(size_t)row * IN_F + k0 + k8l * 8];
            const float4 a = sp[0], b = sp[1];
            const float f[8] = {a.x, a.y, a.z, a.w, b.x, b.y, b.z, b.w};
            union { ushort u[8]; bf16x8_t v; } o;
#pragma unroll
            for (int j = 0; j < 8; ++j) {
                __hip_bfloat16 hb = __float2bfloat16(f[j]);
                o.u[j] = *reinterpret_cast<ushort*>(&hb);
            }
            unsigned byteoff = (unsigned)(row * 2048 + k8l * 16);
            byteoff ^= (unsigned)((row & 7) << 4);       // T2 XOR swizzle
            *(bf16x8_t*)((char*)lds_x + byteoff) = o.v;
        }
    }
    __syncthreads();

    const unsigned xorv = (unsigned)((ln & 7) << 4);     // af-read swizzle

    f32x4_t acc[4][2];
#pragma unroll
    for (int mi = 0; mi < 4; ++mi)
#pragma unroll
        for (int nj = 0; nj < 2; ++nj) acc[mi][nj] = (f32x4_t)0.0f;

#pragma unroll 1
    for (int g = 0; g < 8; ++g) {               // 8 quant groups of 128 K
        // ---- prefetch group g+1 BEFORE computing group g, pinned ----
        unsigned qn[4][2]; float svn[2]; unsigned zwn[2];
        if (g < 7) {
            const int qrow1 = qrowb + (g + 1) * 16;
#pragma unroll
            for (int kt = 0; kt < 4; ++kt)
#pragma unroll
                for (int nj = 0; nj < 2; ++nj)
                    qn[kt][nj] = (unsigned)qw[(size_t)(qrow1 + kt * 4 + kb) * OUT_F +
                                              colbase + nj * 16 + ln];
#pragma unroll
            for (int nj = 0; nj < 2; ++nj) {
                const int c = colbase + nj * 16 + ln;
                svn[nj] = sc[(gbase + g + 1) * OUT_F + c];
                zwn[nj] = (unsigned)qz[(gbase + g + 1) * (OUT_F / 8) + (c >> 3)];
            }
            __builtin_amdgcn_sched_barrier(0);  // loads stay ABOVE the compute
        }

        float s[2], dz[2];
#pragma unroll
        for (int nj = 0; nj < 2; ++nj) {
            const unsigned zp = ((zwc[nj] >> ((ln & 7) * 4)) + 1u) & 15u;  // zp-1 stored
            s[nj]  = svc[nj];
            dz[nj] = -(float)zp * svc[nj];      // w = nib*s + dz
        }

#pragma unroll
        for (int kt = 0; kt < 4; ++kt) {        // 4 K-steps of 32
            // kbyte bits (4..10) don't overlap row bits (>=11): XOR foldable
            const unsigned kbyte = (unsigned)(g * 256 + kt * 64 + kb * 16) ^ xorv;
            bf16x8_t af[4];
#pragma unroll
            for (int mi = 0; mi < 4; ++mi)
                af[mi] = *(const bf16x8_t*)((const char*)lds_x +
                            (unsigned)((mi * 16 + ln) * 2048) + kbyte);
#pragma unroll
            for (int nj = 0; nj < 2; ++nj) {
                const unsigned qv  = qc[kt][nj];
                const unsigned qlo = qv & 0x0F0F0F0Fu;         // nibbles 0,2,4,6
                const unsigned qhi = (qv >> 4) & 0x0F0F0F0Fu;  // nibbles 1,3,5,7
                union { ushort u[8]; bf16x8_t v; } bu;
#pragma unroll
                for (int b = 0; b < 4; ++b) {
                    const float fe = (float)((qlo >> (8 * b)) & 0xFFu);  // v_cvt_f32_ubyteN
                    const float fo = (float)((qhi >> (8 * b)) & 0xFFu);
                    const float we = fe * s[nj] + dz[nj];
                    const float wo = fo * s[nj] + dz[nj];
                    __hip_bfloat16 he = __float2bfloat16(we);
                    __hip_bfloat16 ho = __float2bfloat16(wo);
                    bu.u[2 * b]     = *reinterpret_cast<ushort*>(&he);
                    bu.u[2 * b + 1] = *reinterpret_cast<ushort*>(&ho);
                }
#pragma unroll
                for (int mi = 0; mi < 4; ++mi)
                    acc[mi][nj] = __builtin_amdgcn_mfma_f32_16x16x32_bf16(
                        af[mi], bu.v, acc[mi][nj], 0, 0, 0);
            }
        }

        if (g < 7) {                            // rotate prefetch buffers
#pragma unroll
            for (int kt = 0; kt < 4; ++kt)
#pragma unroll
                for (int nj = 0; nj < 2; ++nj) qc[kt][nj] = qn[kt][nj];
#pragma unroll
            for (int nj = 0; nj < 2; ++nj) { svc[nj] = svn[nj]; zwc[nj] = zwn[nj]; }
        }
    }

    // ---- epilogue: bf16 fragment-major partials, one 64B store/thread ----
    union { ushort u[32]; u16x8_t v8[4]; } ob;
#pragma unroll
    for (int mi = 0; mi < 4; ++mi)
#pragma unroll
        for (int nj = 0; nj < 2; ++nj)
#pragma unroll
            for (int j = 0; j < 4; ++j) {
                __hip_bfloat16 h = __float2bfloat16(acc[mi][nj][j]);
                ob.u[(mi * 2 + nj) * 4 + j] = *reinterpret_cast<ushort*>(&h);
            }
    u16x8_t* pb = (u16x8_t*)part + ((size_t)(ks * 32 + nt) * 512 + threadIdx.x) * 4;
#pragma unroll
    for (int i = 0; i < 4; ++i) pb[i] = ob.v8[i];
}

// ---------------------------------------------------------------------------
// Stage B: sum 8 bf16 K-split partials (fragment layout) + bias -> out.
// Each output element written exactly once. 65536 threads.
// ---------------------------------------------------------------------------
__global__ void __launch_bounds__(256)
wol_reduce(const ushort* __restrict__ part,
           const float*  __restrict__ bias,
           float* __restrict__ out) {
    const int u   = blockIdx.x * 256 + threadIdx.x;
    const int v8  = u & 3;               // which ushort8 of the thread's 32
    const int tid = (u >> 2) & 511;      // stage-A thread id
    const int nt  = u >> 11;             // stage-A N-tile

    float s[8];
#pragma unroll
    for (int e = 0; e < 8; ++e) s[e] = 0.0f;
#pragma unroll
    for (int ks = 0; ks < KSPLIT; ++ks) {
        const u16x8_t p = *((const u16x8_t*)part +
                            (((size_t)(ks * 32 + nt) * 512 + tid) * 4 + v8));
#pragma unroll
        for (int e = 0; e < 8; ++e) {
            union { unsigned b; float f; } cv;
            cv.b = ((unsigned)(ushort)p[e]) << 16;   // bf16 -> f32 exact
            s[e] += cv.f;
        }
    }

    const int wid = tid >> 6, lane = tid & 63;
    const int ln = lane & 15, kb = lane >> 4;
#pragma unroll
    for (int e = 0; e < 8; ++e) {
        const int idx = v8 * 8 + e;                  // (mi*2+nj)*4 + j
        const int mi = idx >> 3, nj = (idx >> 2) & 1, j = idx & 3;
        const int row = mi * 16 + kb * 4 + j;
        const int col = nt * 256 + wid * 32 + nj * 16 + ln;
        out[(size_t)row * OUT_F + col] = s[e] + bias[col];
    }
}

extern "C" void kernel_launch(void* const* d_in, const int* in_sizes, int n_in,
                              void* d_out, int out_size, void* d_ws, size_t ws_size,
                              hipStream_t stream) {
    const float* x    = (const float*)d_in[0];
    const int*   qw   = (const int*)d_in[1];
    const int*   qz   = (const int*)d_in[2];
    const float* sc   = (const float*)d_in[3];
    const float* bias = (const float*)d_in[4];
    float* out = (float*)d_out;

    ushort* prt = (ushort*)d_ws;                 // 8 MiB bf16 partials

    (void)in_sizes; (void)n_in; (void)ws_size; (void)out_size;

    wol_mfma<<<256, 512, 0, stream>>>(x, qw, qz, sc, prt);
    wol_reduce<<<256, 256, 0, stream>>>(prt, bias, out);
}